// Round 3
// baseline (785.980 us; speedup 1.0000x reference)
//
#include <hip/hip_runtime.h>
#include <hip/hip_bf16.h>
#include <math.h>

#define EXP_E 8
#define NCLS 1000
#define DFEAT 59
#define EPSF 1e-8f
#define LN_EPSF 1e-5f

__device__ __forceinline__ float wave_allsum(float v) {
#pragma unroll
  for (int m = 32; m; m >>= 1) v += __shfl_xor(v, m, 64);
  return v;
}

// all-reduce within 32-lane halves (xor masks <= 16 stay inside each half)
__device__ __forceinline__ float half_allsum(float v) {
#pragma unroll
  for (int m = 16; m; m >>= 1) v += __shfl_xor(v, m, 64);
  return v;
}

// branchless sorted insert (descending t0..t4); probs are > 0, init -1
#define INS5(px)                                            \
  {                                                         \
    float x_ = (px), m_;                                    \
    m_ = fmaxf(t0, x_); x_ = fminf(t0, x_); t0 = m_;        \
    m_ = fmaxf(t1, x_); x_ = fminf(t1, x_); t1 = m_;        \
    m_ = fmaxf(t2, x_); x_ = fminf(t2, x_); t2 = m_;        \
    m_ = fmaxf(t3, x_); x_ = fminf(t3, x_); t3 = m_;        \
    t4 = fmaxf(t4, x_);                                     \
  }

// kl recovered later as (sum p*logp) - (sum p*logmp): saves a sub per elem
#define ACCUM(pv, mv, lmv)                                  \
  {                                                         \
    float p_ = (pv);                                        \
    float lp_ = __logf(p_ + EPSF);                          \
    splogp += p_ * lp_;                                     \
    sq += p_ * p_;                                          \
    dot += p_ * (mv);                                       \
    splmp += p_ * (lmv);                                    \
    INS5(p_);                                               \
  }

// ---------------- Kernel 1: feature extraction ----------------
// 512 threads per batch row. Pass A is fused into the staging load: each of
// 500 threads loads 2 classes x 8 experts (float2 per expert, coalesced),
// writes them to LDS, and computes the cross-expert stats from registers.
__global__ __launch_bounds__(512, 4) void feat_kernel(const float* __restrict__ post,
                                                      float* __restrict__ fout) {
  __shared__ __align__(16) float sp[EXP_E * NCLS];   // 32000 B
  __shared__ __align__(16) float smp[NCLS];          // mean over experts
  __shared__ __align__(16) float slmp[NCLS];         // log(mean_p + eps)
  __shared__ float sred[24];                         // 8 waves x 3 stats
  __shared__ float sfeat[DFEAT];

  const int tid = threadIdx.x;
  const int b = blockIdx.x;
  const float* pb = post + (size_t)b * (EXP_E * NCLS);

  // ---- fused stage + pass A ----
  float a_ment = 0.f, a_mvar = 0.f, a_mn2 = 0.f;
  if (tid < 500) {
    const float2* pb2 = reinterpret_cast<const float2*>(pb);
    float2 v[EXP_E];
#pragma unroll
    for (int e2 = 0; e2 < EXP_E; ++e2) v[e2] = pb2[e2 * 500 + tid];
    float2* sp2 = reinterpret_cast<float2*>(sp);
#pragma unroll
    for (int e2 = 0; e2 < EXP_E; ++e2) sp2[e2 * 500 + tid] = v[e2];
    float vv[EXP_E][2];
#pragma unroll
    for (int e2 = 0; e2 < EXP_E; ++e2) { vv[e2][0] = v[e2].x; vv[e2][1] = v[e2].y; }
    float mpj[2], lmj[2];
#pragma unroll
    for (int j = 0; j < 2; ++j) {
      float s1 = 0.f;
#pragma unroll
      for (int e2 = 0; e2 < EXP_E; ++e2) s1 += vv[e2][j];
      float mp = s1 * 0.125f;
      float q = 0.f;
#pragma unroll
      for (int e2 = 0; e2 < EXP_E; ++e2) { float d = vv[e2][j] - mp; q += d * d; }
      a_mvar += q * (1.f / 7.f);  // ddof=1 variance across experts
      float lmp = __logf(mp + EPSF);
      a_ment += mp * lmp;
      a_mn2 += mp * mp;
      mpj[j] = mp; lmj[j] = lmp;
    }
    reinterpret_cast<float2*>(smp)[tid]  = make_float2(mpj[0], mpj[1]);
    reinterpret_cast<float2*>(slmp)[tid] = make_float2(lmj[0], lmj[1]);
  }
  a_ment = wave_allsum(a_ment);
  a_mvar = wave_allsum(a_mvar);
  a_mn2 = wave_allsum(a_mn2);
  const int wv = tid >> 6;
  if ((tid & 63) == 0) {
    sred[wv * 3 + 0] = a_ment;
    sred[wv * 3 + 1] = a_mvar;
    sred[wv * 3 + 2] = a_mn2;
  }
  __syncthreads();  // publishes sp/smp/slmp/sred
  float s_ment = 0.f, s_mvar = 0.f, s_mn2 = 0.f;
#pragma unroll
  for (int w = 0; w < 8; ++w) {
    s_ment += sred[w * 3 + 0];
    s_mvar += sred[w * 3 + 1];
    s_mn2  += sred[w * 3 + 2];
  }
  const float mn = fmaxf(sqrtf(s_mn2), EPSF);

  // ---- pass B: wave w = expert w; 64 lanes, float4 strided ----
  const int e = tid >> 6;
  const int lane = tid & 63;
  float splogp = 0.f, sq = 0.f, dot = 0.f, splmp = 0.f;
  float t0 = -1.f, t1 = -1.f, t2 = -1.f, t3 = -1.f, t4 = -1.f;
  const float4* spe4 = reinterpret_cast<const float4*>(sp + e * NCLS);
  const float4* smp4 = reinterpret_cast<const float4*>(smp);
  const float4* slm4 = reinterpret_cast<const float4*>(slmp);
  for (int k = lane; k < 250; k += 64) {  // last iter: lanes < 58
    float4 p4 = spe4[k];
    float4 m4 = smp4[k];
    float4 l4 = slm4[k];
    ACCUM(p4.x, m4.x, l4.x);
    ACCUM(p4.y, m4.y, l4.y);
    ACCUM(p4.z, m4.z, l4.z);
    ACCUM(p4.w, m4.w, l4.w);
  }
  splogp = wave_allsum(splogp);
  sq     = wave_allsum(sq);
  dot    = wave_allsum(dot);
  splmp  = wave_allsum(splmp);
  // butterfly merge of per-lane sorted top-5 lists across all 64 lanes
#pragma unroll
  for (int m = 1; m <= 32; m <<= 1) {
    float o0 = __shfl_xor(t0, m, 64), o1 = __shfl_xor(t1, m, 64), o2 = __shfl_xor(t2, m, 64),
          o3 = __shfl_xor(t3, m, 64), o4 = __shfl_xor(t4, m, 64);
    float r0 = fmaxf(t0, o0);
    float r1 = fmaxf(fmaxf(t1, o1), fminf(t0, o0));
    float r2 = fmaxf(fmaxf(t2, o2), fmaxf(fminf(t1, o0), fminf(t0, o1)));
    float r3 = fmaxf(fmaxf(t3, o3),
                     fmaxf(fminf(t2, o0), fmaxf(fminf(t1, o1), fminf(t0, o2))));
    float r4 = fmaxf(fmaxf(t4, o4),
                     fmaxf(fmaxf(fminf(t3, o0), fminf(t2, o1)),
                           fmaxf(fminf(t1, o2), fminf(t0, o3))));
    t0 = r0; t1 = r1; t2 = r2; t3 = r3; t4 = r4;
  }

  if (lane == 0) {
    float mass = t0 + t1 + t2 + t3 + t4;
    float pn = fmaxf(sqrtf(sq), EPSF);
    sfeat[0 * 8 + e] = -splogp;          // entropy
    sfeat[1 * 8 + e] = mass;             // topk_mass
    sfeat[2 * 8 + e] = 1.f - mass;       // residual
    sfeat[3 * 8 + e] = t0;               // max_probs
    sfeat[4 * 8 + e] = t0 - t1;          // top_gap
    sfeat[5 * 8 + e] = dot / (pn * mn);  // cos
    sfeat[6 * 8 + e] = splogp - splmp;   // kl
  }
  __syncthreads();
  if (tid == 0) {
    float s = 0.f;
#pragma unroll
    for (int i = 0; i < 8; ++i) s += sfeat[24 + i];
    float mu = s * 0.125f;
    float q = 0.f;
#pragma unroll
    for (int i = 0; i < 8; ++i) { float d = sfeat[24 + i] - mu; q += d * d; }
    sfeat[56] = -s_ment;                       // mean_ent
    sfeat[57] = s_mvar * (1.f / (float)NCLS);  // mean_class_var
    sfeat[58] = sqrtf(q * (1.f / 7.f));        // std_max (ddof=1)
  }
  __syncthreads();
  if (tid < DFEAT) {
    float v = sfeat[tid];
    v = fminf(fmaxf(v, -100.f), 100.f);
    fout[(size_t)b * DFEAT + tid] = v;
  }
}

// ---------------- Kernel 2: MLP head ----------------
// 256 threads per 32 rows. Register-blocked GEMVs; LayerNorms run fully in
// registers via shuffle reductions (no LDS round-trip for LN).
__global__ __launch_bounds__(256) void mlp_kernel(
    const float* __restrict__ feats,
    const float* __restrict__ W1, const float* __restrict__ b1,
    const float* __restrict__ g1, const float* __restrict__ be1,
    const float* __restrict__ W2, const float* __restrict__ b2,
    const float* __restrict__ g2, const float* __restrict__ be2,
    const float* __restrict__ W3, const float* __restrict__ b3,
    float* __restrict__ out_w, float* __restrict__ out_l) {
  __shared__ __align__(16) float sfe[32 * 60];    // 7680 B (row-major, pad 60)
  __shared__ __align__(16) float h1T[256 * 36];   // 36864 B (col-major, pad 36)
  __shared__ __align__(16) float h2[32 * 132];    // 16896 B
  __shared__ __align__(16) float sW3[128 * 8];    // 4096 B   (total = 64 KiB)

  const int tid = threadIdx.x;
  const int r0 = blockIdx.x * 32;

  for (int i = tid; i < 32 * DFEAT; i += 256) {
    int r = i / DFEAT;
    int k = i - r * DFEAT;
    sfe[r * 60 + k] = feats[(size_t)r0 * DFEAT + i];
  }
  reinterpret_cast<float4*>(sW3)[tid] = reinterpret_cast<const float4*>(W3)[tid];
  __syncthreads();

  // ---- layer 1: thread owns 4 cols (cg*4+c) x 8 rows (rg*8+r) ----
  const int cg = tid & 63, rg = tid >> 6;  // wave == rg (rows rg*8..+7)
  float acc[4][8];
#pragma unroll
  for (int c = 0; c < 4; ++c)
#pragma unroll
    for (int r = 0; r < 8; ++r) acc[c][r] = 0.f;
  for (int k = 0; k < DFEAT; ++k) {
    float4 w = *reinterpret_cast<const float4*>(W1 + k * 256 + cg * 4);
    float s[8];
#pragma unroll
    for (int r = 0; r < 8; ++r) s[r] = sfe[(rg * 8 + r) * 60 + k];  // broadcast
#pragma unroll
    for (int r = 0; r < 8; ++r) {
      acc[0][r] += s[r] * w.x;
      acc[1][r] += s[r] * w.y;
      acc[2][r] += s[r] * w.z;
      acc[3][r] += s[r] * w.w;
    }
  }
  {
    float4 bb = *reinterpret_cast<const float4*>(b1 + cg * 4);
#pragma unroll
    for (int r = 0; r < 8; ++r) {
      acc[0][r] += bb.x; acc[1][r] += bb.y; acc[2][r] += bb.z; acc[3][r] += bb.w;
    }
  }
  // LN1 + relu in registers: wave = 8 rows; reduce across 64 lanes x 4 cols
  {
    float4 gg = *reinterpret_cast<const float4*>(g1 + cg * 4);
    float4 ee = *reinterpret_cast<const float4*>(be1 + cg * 4);
#pragma unroll
    for (int r = 0; r < 8; ++r) {
      float sum = wave_allsum(acc[0][r] + acc[1][r] + acc[2][r] + acc[3][r]);
      float mu = sum * (1.f / 256.f);
      float d0 = acc[0][r] - mu, d1 = acc[1][r] - mu, d2 = acc[2][r] - mu, d3 = acc[3][r] - mu;
      float q = wave_allsum(d0 * d0 + d1 * d1 + d2 * d2 + d3 * d3);
      float inv = 1.0f / sqrtf(q * (1.f / 256.f) + LN_EPSF);
      acc[0][r] = fmaxf(d0 * inv * gg.x + ee.x, 0.f);
      acc[1][r] = fmaxf(d1 * inv * gg.y + ee.y, 0.f);
      acc[2][r] = fmaxf(d2 * inv * gg.z + ee.z, 0.f);
      acc[3][r] = fmaxf(d3 * inv * gg.w + ee.w, 0.f);
    }
  }
  // write transposed h1T[col][row] as 2 x b128 per col
#pragma unroll
  for (int c = 0; c < 4; ++c) {
    float* dst = h1T + (cg * 4 + c) * 36 + rg * 8;
    *reinterpret_cast<float4*>(dst)     = make_float4(acc[c][0], acc[c][1], acc[c][2], acc[c][3]);
    *reinterpret_cast<float4*>(dst + 4) = make_float4(acc[c][4], acc[c][5], acc[c][6], acc[c][7]);
  }
  __syncthreads();

  // ---- layer 2: thread owns 4 cols (cg2*4+c) x 4 rows (rg2*4+r) ----
  const int cg2 = tid & 31, rg2 = tid >> 5;  // half-wave == rg2
  float a2[4][4];
#pragma unroll
  for (int c = 0; c < 4; ++c)
#pragma unroll
    for (int r = 0; r < 4; ++r) a2[c][r] = 0.f;
  for (int k = 0; k < 256; ++k) {
    float4 h = *reinterpret_cast<const float4*>(h1T + k * 36 + rg2 * 4);  // 4 rows
    float4 w = *reinterpret_cast<const float4*>(W2 + k * 128 + cg2 * 4);  // 4 cols
    float hr[4] = {h.x, h.y, h.z, h.w};
    float wc[4] = {w.x, w.y, w.z, w.w};
#pragma unroll
    for (int c = 0; c < 4; ++c)
#pragma unroll
      for (int r = 0; r < 4; ++r) a2[c][r] += hr[r] * wc[c];
  }
  {
    float4 bb = *reinterpret_cast<const float4*>(b2 + cg2 * 4);
#pragma unroll
    for (int r = 0; r < 4; ++r) {
      a2[0][r] += bb.x; a2[1][r] += bb.y; a2[2][r] += bb.z; a2[3][r] += bb.w;
    }
  }
  // LN2 + relu in registers: 32-lane group (same rg2) x 4 cols = 128
  {
    float4 gg = *reinterpret_cast<const float4*>(g2 + cg2 * 4);
    float4 ee = *reinterpret_cast<const float4*>(be2 + cg2 * 4);
#pragma unroll
    for (int r = 0; r < 4; ++r) {
      float sum = half_allsum(a2[0][r] + a2[1][r] + a2[2][r] + a2[3][r]);
      float mu = sum * (1.f / 128.f);
      float d0 = a2[0][r] - mu, d1 = a2[1][r] - mu, d2 = a2[2][r] - mu, d3 = a2[3][r] - mu;
      float q = half_allsum(d0 * d0 + d1 * d1 + d2 * d2 + d3 * d3);
      float inv = 1.0f / sqrtf(q * (1.f / 128.f) + LN_EPSF);
      a2[0][r] = fmaxf(d0 * inv * gg.x + ee.x, 0.f);
      a2[1][r] = fmaxf(d1 * inv * gg.y + ee.y, 0.f);
      a2[2][r] = fmaxf(d2 * inv * gg.z + ee.z, 0.f);
      a2[3][r] = fmaxf(d3 * inv * gg.w + ee.w, 0.f);
    }
  }
#pragma unroll
  for (int r = 0; r < 4; ++r)
    *reinterpret_cast<float4*>(h2 + (rg2 * 4 + r) * 132 + cg2 * 4) =
        make_float4(a2[0][r], a2[1][r], a2[2][r], a2[3][r]);
  __syncthreads();

  // ---- layer 3 + softmax: thread = (row, expert) ----
  {
    const int r = tid >> 3, e = tid & 7;
    float s = b3[e];
    const float4* hrow = reinterpret_cast<const float4*>(h2 + r * 132);
#pragma unroll
    for (int k4 = 0; k4 < 32; ++k4) {
      float4 h = hrow[k4];
      s += h.x * sW3[(k4 * 4 + 0) * 8 + e];
      s += h.y * sW3[(k4 * 4 + 1) * 8 + e];
      s += h.z * sW3[(k4 * 4 + 2) * 8 + e];
      s += h.w * sW3[(k4 * 4 + 3) * 8 + e];
    }
    float m = s;
#pragma unroll
    for (int mk = 4; mk; mk >>= 1) m = fmaxf(m, __shfl_xor(m, mk, 64));
    float ex = __expf(s - m);
    float den = ex;
#pragma unroll
    for (int mk = 4; mk; mk >>= 1) den += __shfl_xor(den, mk, 64);
    out_l[(size_t)(r0 + r) * 8 + e] = s;
    out_w[(size_t)(r0 + r) * 8 + e] = ex / den;
  }
}

extern "C" void kernel_launch(void* const* d_in, const int* in_sizes, int n_in,
                              void* d_out, int out_size, void* d_ws, size_t ws_size,
                              hipStream_t stream) {
  const float* post = (const float*)d_in[0];
  const float* W1  = (const float*)d_in[1];
  const float* b1  = (const float*)d_in[2];
  const float* g1  = (const float*)d_in[3];
  const float* be1 = (const float*)d_in[4];
  const float* W2  = (const float*)d_in[5];
  const float* b2  = (const float*)d_in[6];
  const float* g2  = (const float*)d_in[7];
  const float* be2 = (const float*)d_in[8];
  const float* W3  = (const float*)d_in[9];
  const float* b3  = (const float*)d_in[10];

  float* out = (float*)d_out;
  const int B = in_sizes[0] / (EXP_E * NCLS);  // 16384

  float* out_w = out;                       // weights (B,8)
  float* out_l = out + (size_t)B * 8;       // logits  (B,8)
  float* fout  = out + (size_t)2 * B * 8;   // feats   (B,59)

  hipLaunchKernelGGL(feat_kernel, dim3(B), dim3(512), 0, stream, post, fout);
  hipLaunchKernelGGL(mlp_kernel, dim3(B / 32), dim3(256), 0, stream,
                     fout, W1, b1, g1, be1, W2, b2, g2, be2, W3, b3, out_w, out_l);
}